// Round 5
// baseline (206.580 us; speedup 1.0000x reference)
//
#include <hip/hip_runtime.h>
#include <hip/hip_bf16.h>

// B=256, d=2048, N0=7936, N=8192, K=128, P=2, ALPHA=BETA=1, EPS=1e-12
#define BDIM 256
#define DDIM 2048
#define NGAL 7936
#define NTOT 8192
#define TOPK 128
#define EPSC 1e-12f

typedef __attribute__((ext_vector_type(8))) short bf16x8;
typedef __attribute__((ext_vector_type(4))) float f32x4;
typedef unsigned long long u64;

// round-to-nearest-even fp32 -> bf16 (bit pattern in a short)
__device__ __forceinline__ short bfr(float x) {
  unsigned u = __float_as_uint(x);
  unsigned r = (u + 0x7FFFu + ((u >> 16) & 1u)) >> 16;
  return (short)r;
}

// ---------------- Kernel 1: gallery bf16+norms  +  teacher/student prep ----
__global__ __launch_bounds__(256) void k_prep_gal(
    const float* __restrict__ f_t, const float* __restrict__ f_s,
    const float* __restrict__ gallery, short* __restrict__ Abf,
    short* __restrict__ Bbf, float* __restrict__ normA,
    float* __restrict__ galnorm) {
  int bx = blockIdx.x, t = threadIdx.x;
  int lane = t & 63, wv = t >> 6;
  if (bx < NGAL / 4) {
    int row = bx * 4 + wv;
    const float4* g4 = (const float4*)(gallery + (size_t)row * DDIM);
    float s = 0.f;
    for (int i = lane; i < DDIM / 4; i += 64) {
      float4 v = g4[i];
      *(short4*)&Bbf[(size_t)row * DDIM + i * 4] =
          make_short4(bfr(v.x), bfr(v.y), bfr(v.z), bfr(v.w));
      s += v.x * v.x + v.y * v.y + v.z * v.z + v.w * v.w;
    }
    for (int off = 32; off; off >>= 1) s += __shfl_xor(s, off);
    if (lane == 0) galnorm[row] = s;
    return;
  }
  int b = bx - NGAL / 4;
  const float4* t4 = (const float4*)(f_t + (size_t)b * DDIM);
  const float4* s4 = (const float4*)(f_s + (size_t)b * DDIM);
  float st = 0.f, ss = 0.f;
  for (int i = t; i < DDIM / 4; i += 256) {
    float4 v = t4[i];
    float4 q = make_float4(v.x * v.x, v.y * v.y, v.z * v.z, v.w * v.w);
    short4 qb = make_short4(bfr(q.x), bfr(q.y), bfr(q.z), bfr(q.w));
    *(short4*)&Abf[(size_t)b * DDIM + i * 4] = qb;
    *(short4*)&Bbf[(size_t)(NGAL + b) * DDIM + i * 4] = qb;
    st += q.x * q.x + q.y * q.y + q.z * q.z + q.w * q.w;
    float4 u_ = s4[i];
    float4 r = make_float4(u_.x * u_.x, u_.y * u_.y, u_.z * u_.z, u_.w * u_.w);
    *(short4*)&Abf[(size_t)(BDIM + b) * DDIM + i * 4] =
        make_short4(bfr(r.x), bfr(r.y), bfr(r.z), bfr(r.w));
    ss += r.x * r.x + r.y * r.y + r.z * r.z + r.w * r.w;
  }
  for (int off = 32; off; off >>= 1) {
    st += __shfl_xor(st, off);
    ss += __shfl_xor(ss, off);
  }
  __shared__ float red[8];
  if (lane == 0) { red[wv] = st; red[4 + wv] = ss; }
  __syncthreads();
  if (t == 0) {
    float a = red[0] + red[1] + red[2] + red[3];
    float c = red[4] + red[5] + red[6] + red[7];
    normA[b] = a;
    galnorm[NGAL + b] = a;
    normA[BDIM + b] = c;
  }
}

// ---------------- Kernel 2: bf16 MFMA GEMM -> clipped squared distances ----
// 64(M)x128(N) tile, BK=64, 4 waves (2x2), double-buffered LDS via
// global_load_lds (linear dest; pre-swizzled global source; swizzled reads).
__global__ __launch_bounds__(256) void k_gemm(
    const short* __restrict__ Abf, const short* __restrict__ Bbf,
    const float* __restrict__ normA, const float* __restrict__ galnorm,
    float* __restrict__ d2) {
  __shared__ short S[2][12288];  // [0,4096): A 64x64 ; [4096,12288): B 128x64
  int t = threadIdx.x;
  int n0 = blockIdx.x * 128, m0 = blockIdx.y * 64;
  int lane = t & 63, wid = t >> 6;
  int wm = wid >> 1, wn = wid & 1;

  const short* gb[6];
  int lof[6];
#pragma unroll
  for (int q = 0; q < 6; ++q) {
    int c = t + q * 256;
    int r, j;
    const short* base;
    if (c < 512) {
      r = c >> 3; j = c & 7;
      base = Abf + (size_t)(m0 + r) * DDIM;
    } else {
      int cb = c - 512;
      r = cb >> 3; j = cb & 7;
      base = Bbf + (size_t)(n0 + r) * DDIM;
    }
    gb[q] = base + ((j * 8) ^ ((r & 7) << 3));
    lof[q] = c * 8;
  }

  int fr = lane & 15, fk = (lane >> 4) * 8;
  int axor = (fr & 7) << 3;
  f32x4 acc[2][4] = {};

#define STAGE(buf, kt)                                                       \
  {                                                                          \
    _Pragma("unroll") for (int q = 0; q < 6; ++q)                            \
        __builtin_amdgcn_global_load_lds(                                    \
            (const __attribute__((address_space(1))) void*)(gb[q] + (kt)),   \
            (__attribute__((address_space(3))) void*)(&S[buf][lof[q]]), 16,  \
            0, 0);                                                           \
  }

  STAGE(0, 0);
  __syncthreads();
  int cur = 0;
  for (int it = 0; it < DDIM / 64; ++it) {
    if (it + 1 < DDIM / 64) STAGE(cur ^ 1, (it + 1) * 64);
#pragma unroll
    for (int ks = 0; ks < 2; ++ks) {
      int ko = (ks * 32 + fk) ^ axor;
      bf16x8 av[2], bv[4];
#pragma unroll
      for (int mi = 0; mi < 2; ++mi)
        av[mi] = *(const bf16x8*)&S[cur][(wm * 32 + mi * 16 + fr) * 64 + ko];
#pragma unroll
      for (int ni = 0; ni < 4; ++ni)
        bv[ni] =
            *(const bf16x8*)&S[cur][4096 + (wn * 64 + ni * 16 + fr) * 64 + ko];
#pragma unroll
      for (int mi = 0; mi < 2; ++mi)
#pragma unroll
        for (int ni = 0; ni < 4; ++ni)
          acc[mi][ni] = __builtin_amdgcn_mfma_f32_16x16x32_bf16(
              av[mi], bv[ni], acc[mi][ni], 0, 0, 0);
    }
    __syncthreads();
    cur ^= 1;
  }
  int rrow = (lane >> 4) * 4;
#pragma unroll
  for (int mi = 0; mi < 2; ++mi) {
#pragma unroll
    for (int r = 0; r < 4; ++r) {
      int m = m0 + wm * 32 + mi * 16 + rrow + r;
      float nm = normA[m];
#pragma unroll
      for (int ni = 0; ni < 4; ++ni) {
        int n = n0 + wn * 64 + ni * 16 + fr;
        float v = nm + galnorm[n] - 2.0f * acc[mi][ni][r];
        v = fmaxf(v, EPSC);
        if (m < BDIM && n == NGAL + m) v = EPSC;  // exact self-match pin
        d2[(size_t)m * NTOT + n] = v;
      }
    }
  }
#undef STAGE
}

// ---------------- Kernel 3: per-chunk exact top-128 radix select -----------
// Block (c, b): columns [c*2048,(c+1)*2048) of teacher row b. Unique 43-bit
// keys (u32<<11)|local_idx, 4 passes x 11 bits. Histogram atomics are
// wave-leader aggregated (one atomicAdd per distinct bin per wave batch) --
// pass 0 is near-degenerate (values cluster in ~8 bins) so raw atomics
// serialize. Permuted slots keep the summation phase conflict-free.
__global__ __launch_bounds__(256) void k_part(
    const float* __restrict__ d2, u64* __restrict__ cand) {
  __shared__ unsigned rowu[2048];
  __shared__ unsigned hist[2][2048];
  __shared__ unsigned wsum[4];
  __shared__ u64 s_pref;
  __shared__ unsigned s_kneed, s_cnt;
  int c = blockIdx.x, b = blockIdx.y, t = threadIdx.x;
  int lane = t & 63, w = t >> 6;
  const uint4* src = (const uint4*)(d2 + (size_t)b * NTOT + c * 2048);
  ((uint4*)rowu)[t] = src[t];
  ((uint4*)rowu)[t + 256] = src[t + 256];
  if (t == 0) { s_pref = 0; s_kneed = TOPK; s_cnt = 0; }
#pragma unroll 1
  for (int p = 0; p < 4; ++p) {
    int sh = 33 - 11 * p;
    for (int i = t; i < 4096; i += 256) (&hist[0][0])[i] = 0;
    __syncthreads();  // zero + rowu + prev winner visible
    u64 pref = s_pref;
    unsigned kn = s_kneed;
#pragma unroll 1
    for (int s = 0; s < 8; ++s) {
      int i = t + s * 256;
      u64 key = ((u64)rowu[i] << 11) | (unsigned)i;
      bool pred = ((key >> (sh + 11)) == pref);
      unsigned bin = (unsigned)(key >> sh) & 2047u;
      unsigned slot = ((bin & 7u) << 8) | (bin >> 3);
      u64 todo = __ballot(pred);
      while (todo) {
        int leader = (int)(__ffsll((long long)todo) - 1);
        unsigned lslot = (unsigned)__shfl((int)slot, leader);
        u64 same = __ballot(slot == lslot) & todo;
        if (lane == leader)
          atomicAdd(&hist[w & 1][lslot], (unsigned)__popcll(same));
        todo &= ~same;
      }
    }
    __syncthreads();
    unsigned ls = 0;  // sum of bins [8t, 8t+8) == slots q*256+t
#pragma unroll
    for (int q = 0; q < 8; ++q)
      ls += hist[0][q * 256 + t] + hist[1][q * 256 + t];
    unsigned incl = ls;
    for (int off = 1; off < 64; off <<= 1) {
      unsigned x = __shfl_up(incl, off);
      if (lane >= off) incl += x;
    }
    if (lane == 63) wsum[w] = incl;
    __syncthreads();
    unsigned woff = 0;
    for (int ww = 0; ww < w; ++ww) woff += wsum[ww];
    incl += woff;
    unsigned excl = incl - ls;
    if (excl < kn && kn <= incl) {  // unique winner thread
      unsigned re = excl, binj = 0;
      for (int q = 0; q < 8; ++q) {
        unsigned h = hist[0][q * 256 + t] + hist[1][q * 256 + t];
        if (kn <= re + h) { binj = ((unsigned)t << 3) | (unsigned)q; break; }
        re += h;
      }
      s_pref = (pref << 11) | binj;
      s_kneed = kn - re;
    }
    __syncthreads();
  }
  u64 kstar = s_pref;  // exact 128th-smallest key of this chunk
  u64* dst = cand + ((size_t)b * 4 + c) * TOPK;
#pragma unroll
  for (int s = 0; s < 8; ++s) {
    int i = t + s * 256;
    unsigned u = rowu[i];
    u64 key = ((u64)u << 11) | (unsigned)i;
    if (key <= kstar) {
      unsigned pos = atomicAdd(&s_cnt, 1u);
      dst[pos] = ((u64)u << 13) | (unsigned)(c * 2048 + i);
    }
  }
}

// ---------------- Kernel 4: sort-free merge + loss -------------------------
// 512 unique candidate keys per row; global rank of key = #{smaller keys}
// (exact for ranks < 128 since every globally-smaller key is present).
// rank r < 128 -> slot r. Loss is order-free given the min pair (rank 0):
// full-set rank sums minus the min-pair term reproduce t_value[1:] ranks.
__global__ __launch_bounds__(256) void k_mloss(
    const u64* __restrict__ cand, const float* __restrict__ d2,
    float* __restrict__ out) {
  __shared__ u64 sk[512];
  __shared__ float tvs[TOPK], svs[TOPK], red[2];
  int b = blockIdx.x, t = threadIdx.x;
  u64 k0 = cand[(size_t)b * 512 + t];
  u64 k1 = cand[(size_t)b * 512 + 256 + t];
  sk[t] = k0;
  sk[t + 256] = k1;
  __syncthreads();
  int r0 = 0, r1 = 0;
  for (int j = 0; j < 512; ++j) {  // LDS broadcast reads (lockstep j)
    u64 kj = sk[j];
    r0 += (kj < k0);
    r1 += (kj < k1);
  }
  const float* srow = d2 + (size_t)(BDIM + b) * NTOT;
  if (r0 < TOPK) {
    tvs[r0] = sqrtf(__uint_as_float((unsigned)(k0 >> 13)));
    svs[r0] = sqrtf(srow[(unsigned)(k0 & 8191u)]);
  }
  if (r1 < TOPK) {
    tvs[r1] = sqrtf(__uint_as_float((unsigned)(k1 >> 13)));
    svs[r1] = sqrtf(srow[(unsigned)(k1 & 8191u)]);
  }
  __syncthreads();
  float val = 0.f;
  if (t >= 1 && t < TOPK) {
    float tv = tvs[t], sv = svs[t];
    float tr = 0.f, sr = 0.f;
    for (int j = 0; j < TOPK; ++j) {
      tr += fmaxf(tv - tvs[j], 0.f);
      sr += fmaxf(sv - svs[j], 0.f);
    }
    tr -= fmaxf(tv - tvs[0], 0.f);  // exclude min pair (reference uses [1:])
    sr -= fmaxf(sv - svs[0], 0.f);
    float d = tr - sr;
    val = d * d;
  }
  int lane = t & 63, w = t >> 6;
  for (int off = 1; off < 64; off <<= 1) val += __shfl_xor(val, off);
  if (lane == 0) red[w] = val;  // threads >=128 contribute 0
  __syncthreads();
  if (t == 0) {
    float sum = red[0] + red[1];
    float contrib = (1.f / 256.f) * fabsf(svs[0] - tvs[0]) +
                    (1.f / (127.f * 256.f)) * sqrtf(sum);
    atomicAdd(out, contrib);
  }
}

// ---------------- launch ----------------------------------------------------
extern "C" void kernel_launch(void* const* d_in, const int* in_sizes, int n_in,
                              void* d_out, int out_size, void* d_ws,
                              size_t ws_size, hipStream_t stream) {
  const float* f_s = (const float*)d_in[0];
  const float* f_t = (const float*)d_in[1];
  const float* gallery = (const float*)d_in[2];
  float* out = (float*)d_out;

  float* d2 = (float*)d_ws;                            // 512*8192 f32 (16 MB)
  short* Abf = (short*)(d2 + (size_t)512 * NTOT);      // 512*2048 bf16 (2 MB)
  short* Bbf = Abf + (size_t)512 * DDIM;               // 8192*2048 bf16 (32 MB)
  float* normA = (float*)(Bbf + (size_t)NTOT * DDIM);  // 512
  float* galnorm = normA + 512;                        // 8192
  u64* cand = (u64*)(galnorm + NTOT);                  // 256*512 u64 (1 MB)

  hipMemsetAsync(d_out, 0, sizeof(float), stream);

  k_prep_gal<<<NGAL / 4 + BDIM, 256, 0, stream>>>(f_t, f_s, gallery, Abf, Bbf,
                                                  normA, galnorm);
  k_gemm<<<dim3(NTOT / 128, 512 / 64), 256, 0, stream>>>(Abf, Bbf, normA,
                                                         galnorm, d2);
  k_part<<<dim3(4, BDIM), 256, 0, stream>>>(d2, cand);
  k_mloss<<<BDIM, 256, 0, stream>>>(cand, d2, out);
}

// Round 6
// 163.240 us; speedup vs baseline: 1.2655x; 1.2655x over previous
//
#include <hip/hip_runtime.h>
#include <hip/hip_bf16.h>

// B=256, d=2048, N0=7936, N=8192, K=128, P=2, ALPHA=BETA=1, EPS=1e-12
#define BDIM 256
#define DDIM 2048
#define NGAL 7936
#define NTOT 8192
#define TOPK 128
#define EPSC 1e-12f

typedef __attribute__((ext_vector_type(8))) short bf16x8;
typedef __attribute__((ext_vector_type(4))) float f32x4;
typedef unsigned long long u64;

// round-to-nearest-even fp32 -> bf16 (bit pattern in a short)
__device__ __forceinline__ short bfr(float x) {
  unsigned u = __float_as_uint(x);
  unsigned r = (u + 0x7FFFu + ((u >> 16) & 1u)) >> 16;
  return (short)r;
}

// ---------------- Kernel 1: gallery bf16+norms  +  teacher/student prep ----
__global__ __launch_bounds__(256) void k_prep_gal(
    const float* __restrict__ f_t, const float* __restrict__ f_s,
    const float* __restrict__ gallery, short* __restrict__ Abf,
    short* __restrict__ Bbf, float* __restrict__ normA,
    float* __restrict__ galnorm) {
  int bx = blockIdx.x, t = threadIdx.x;
  int lane = t & 63, wv = t >> 6;
  if (bx < NGAL / 4) {
    int row = bx * 4 + wv;
    const float4* g4 = (const float4*)(gallery + (size_t)row * DDIM);
    float s = 0.f;
    for (int i = lane; i < DDIM / 4; i += 64) {
      float4 v = g4[i];
      *(short4*)&Bbf[(size_t)row * DDIM + i * 4] =
          make_short4(bfr(v.x), bfr(v.y), bfr(v.z), bfr(v.w));
      s += v.x * v.x + v.y * v.y + v.z * v.z + v.w * v.w;
    }
    for (int off = 32; off; off >>= 1) s += __shfl_xor(s, off);
    if (lane == 0) galnorm[row] = s;
    return;
  }
  int b = bx - NGAL / 4;
  const float4* t4 = (const float4*)(f_t + (size_t)b * DDIM);
  const float4* s4 = (const float4*)(f_s + (size_t)b * DDIM);
  float st = 0.f, ss = 0.f;
  for (int i = t; i < DDIM / 4; i += 256) {
    float4 v = t4[i];
    float4 q = make_float4(v.x * v.x, v.y * v.y, v.z * v.z, v.w * v.w);
    short4 qb = make_short4(bfr(q.x), bfr(q.y), bfr(q.z), bfr(q.w));
    *(short4*)&Abf[(size_t)b * DDIM + i * 4] = qb;
    *(short4*)&Bbf[(size_t)(NGAL + b) * DDIM + i * 4] = qb;
    st += q.x * q.x + q.y * q.y + q.z * q.z + q.w * q.w;
    float4 u_ = s4[i];
    float4 r = make_float4(u_.x * u_.x, u_.y * u_.y, u_.z * u_.z, u_.w * u_.w);
    *(short4*)&Abf[(size_t)(BDIM + b) * DDIM + i * 4] =
        make_short4(bfr(r.x), bfr(r.y), bfr(r.z), bfr(r.w));
    ss += r.x * r.x + r.y * r.y + r.z * r.z + r.w * r.w;
  }
  for (int off = 32; off; off >>= 1) {
    st += __shfl_xor(st, off);
    ss += __shfl_xor(ss, off);
  }
  __shared__ float red[8];
  if (lane == 0) { red[wv] = st; red[4 + wv] = ss; }
  __syncthreads();
  if (t == 0) {
    float a = red[0] + red[1] + red[2] + red[3];
    float c = red[4] + red[5] + red[6] + red[7];
    normA[b] = a;
    galnorm[NGAL + b] = a;
    normA[BDIM + b] = c;
  }
}

// ---------------- Kernel 2: bf16 MFMA GEMM -> clipped squared distances ----
// 64(M)x128(N) tile, BK=64, 4 waves (2x2), double-buffered LDS via
// global_load_lds (linear dest; pre-swizzled global source; swizzled reads).
__global__ __launch_bounds__(256) void k_gemm(
    const short* __restrict__ Abf, const short* __restrict__ Bbf,
    const float* __restrict__ normA, const float* __restrict__ galnorm,
    float* __restrict__ d2) {
  __shared__ short S[2][12288];  // [0,4096): A 64x64 ; [4096,12288): B 128x64
  int t = threadIdx.x;
  int n0 = blockIdx.x * 128, m0 = blockIdx.y * 64;
  int lane = t & 63, wid = t >> 6;
  int wm = wid >> 1, wn = wid & 1;

  const short* gb[6];
  int lof[6];
#pragma unroll
  for (int q = 0; q < 6; ++q) {
    int c = t + q * 256;
    int r, j;
    const short* base;
    if (c < 512) {
      r = c >> 3; j = c & 7;
      base = Abf + (size_t)(m0 + r) * DDIM;
    } else {
      int cb = c - 512;
      r = cb >> 3; j = cb & 7;
      base = Bbf + (size_t)(n0 + r) * DDIM;
    }
    gb[q] = base + ((j * 8) ^ ((r & 7) << 3));
    lof[q] = c * 8;
  }

  int fr = lane & 15, fk = (lane >> 4) * 8;
  int axor = (fr & 7) << 3;
  f32x4 acc[2][4] = {};

#define STAGE(buf, kt)                                                       \
  {                                                                          \
    _Pragma("unroll") for (int q = 0; q < 6; ++q)                            \
        __builtin_amdgcn_global_load_lds(                                    \
            (const __attribute__((address_space(1))) void*)(gb[q] + (kt)),   \
            (__attribute__((address_space(3))) void*)(&S[buf][lof[q]]), 16,  \
            0, 0);                                                           \
  }

  STAGE(0, 0);
  __syncthreads();
  int cur = 0;
  for (int it = 0; it < DDIM / 64; ++it) {
    if (it + 1 < DDIM / 64) STAGE(cur ^ 1, (it + 1) * 64);
#pragma unroll
    for (int ks = 0; ks < 2; ++ks) {
      int ko = (ks * 32 + fk) ^ axor;
      bf16x8 av[2], bv[4];
#pragma unroll
      for (int mi = 0; mi < 2; ++mi)
        av[mi] = *(const bf16x8*)&S[cur][(wm * 32 + mi * 16 + fr) * 64 + ko];
#pragma unroll
      for (int ni = 0; ni < 4; ++ni)
        bv[ni] =
            *(const bf16x8*)&S[cur][4096 + (wn * 64 + ni * 16 + fr) * 64 + ko];
#pragma unroll
      for (int mi = 0; mi < 2; ++mi)
#pragma unroll
        for (int ni = 0; ni < 4; ++ni)
          acc[mi][ni] = __builtin_amdgcn_mfma_f32_16x16x32_bf16(
              av[mi], bv[ni], acc[mi][ni], 0, 0, 0);
    }
    __syncthreads();
    cur ^= 1;
  }
  int rrow = (lane >> 4) * 4;
#pragma unroll
  for (int mi = 0; mi < 2; ++mi) {
#pragma unroll
    for (int r = 0; r < 4; ++r) {
      int m = m0 + wm * 32 + mi * 16 + rrow + r;
      float nm = normA[m];
#pragma unroll
      for (int ni = 0; ni < 4; ++ni) {
        int n = n0 + wn * 64 + ni * 16 + fr;
        float v = nm + galnorm[n] - 2.0f * acc[mi][ni][r];
        v = fmaxf(v, EPSC);
        if (m < BDIM && n == NGAL + m) v = EPSC;  // exact self-match pin
        d2[(size_t)m * NTOT + n] = v;
      }
    }
  }
#undef STAGE
}

// ---------------- Kernel 3: per-chunk exact top-128 radix select -----------
// Block (c, b): columns [c*2048,(c+1)*2048) of teacher row b. Unique 43-bit
// keys (u32<<11)|local_idx, 4 passes x 11 bits, 2048-bin hist (2 wave-parity
// copies), permuted slots so the summation phase is conflict-free. Plain
// atomics (leader-aggregation regressed: serial in spread passes, r5).
// Final collect: one s_cnt atomic per wave (ballot prefix).
__global__ __launch_bounds__(256) void k_part(
    const float* __restrict__ d2, u64* __restrict__ cand) {
  __shared__ unsigned rowu[2048];
  __shared__ unsigned hist[2][2048];
  __shared__ unsigned wsum[4];
  __shared__ u64 s_pref;
  __shared__ unsigned s_kneed, s_cnt;
  int c = blockIdx.x, b = blockIdx.y, t = threadIdx.x;
  int lane = t & 63, w = t >> 6;
  const uint4* src = (const uint4*)(d2 + (size_t)b * NTOT + c * 2048);
  ((uint4*)rowu)[t] = src[t];
  ((uint4*)rowu)[t + 256] = src[t + 256];
  if (t == 0) { s_pref = 0; s_kneed = TOPK; s_cnt = 0; }
#pragma unroll 1
  for (int p = 0; p < 4; ++p) {
    int sh = 33 - 11 * p;
    for (int i = t; i < 4096; i += 256) (&hist[0][0])[i] = 0;
    __syncthreads();  // zero + rowu + prev winner visible
    u64 pref = s_pref;
    unsigned kn = s_kneed;
#pragma unroll
    for (int s = 0; s < 8; ++s) {
      int i = t + s * 256;
      u64 key = ((u64)rowu[i] << 11) | (unsigned)i;
      if ((key >> (sh + 11)) == pref) {
        unsigned bin = (unsigned)(key >> sh) & 2047u;
        unsigned slot = ((bin & 7u) << 8) | (bin >> 3);  // conflict-free sums
        atomicAdd(&hist[w & 1][slot], 1u);
      }
    }
    __syncthreads();
    unsigned ls = 0;  // sum of bins [8t, 8t+8) == slots q*256+t
#pragma unroll
    for (int q = 0; q < 8; ++q)
      ls += hist[0][q * 256 + t] + hist[1][q * 256 + t];
    unsigned incl = ls;
    for (int off = 1; off < 64; off <<= 1) {
      unsigned x = __shfl_up(incl, off);
      if (lane >= off) incl += x;
    }
    if (lane == 63) wsum[w] = incl;
    __syncthreads();
    unsigned woff = 0;
    for (int ww = 0; ww < w; ++ww) woff += wsum[ww];
    incl += woff;
    unsigned excl = incl - ls;
    if (excl < kn && kn <= incl) {  // unique winner thread
      unsigned re = excl, binj = 0;
      for (int q = 0; q < 8; ++q) {
        unsigned h = hist[0][q * 256 + t] + hist[1][q * 256 + t];
        if (kn <= re + h) { binj = ((unsigned)t << 3) | (unsigned)q; break; }
        re += h;
      }
      s_pref = (pref << 11) | binj;
      s_kneed = kn - re;
    }
    __syncthreads();
  }
  u64 kstar = s_pref;  // exact 128th-smallest key of this chunk
  u64* dst = cand + ((size_t)b * 4 + c) * TOPK;
#pragma unroll 1
  for (int s = 0; s < 8; ++s) {
    int i = t + s * 256;
    unsigned u = rowu[i];
    u64 key = ((u64)u << 11) | (unsigned)i;
    bool pred = (key <= kstar);
    u64 mask = __ballot(pred);
    unsigned base;
    if (lane == 0) base = atomicAdd(&s_cnt, (unsigned)__popcll(mask));
    base = (unsigned)__shfl((int)base, 0);
    if (pred) {
      unsigned pos = base + (unsigned)__popcll(mask & ((1ull << lane) - 1));
      dst[pos] = ((u64)u << 13) | (unsigned)(c * 2048 + i);
    }
  }
}

// ---------------- Kernel 4: sort-free merge + loss -------------------------
// 512 unique candidate keys per row; global rank of key = #{smaller keys}
// (exact for ranks < 128 since every globally-smaller key is present).
// rank r < 128 -> slot r. Loss is order-free given the min pair (rank 0).
__global__ __launch_bounds__(256) void k_mloss(
    const u64* __restrict__ cand, const float* __restrict__ d2,
    float* __restrict__ out) {
  __shared__ u64 sk[512];
  __shared__ float tvs[TOPK], svs[TOPK], red[2];
  int b = blockIdx.x, t = threadIdx.x;
  u64 k0 = cand[(size_t)b * 512 + t];
  u64 k1 = cand[(size_t)b * 512 + 256 + t];
  sk[t] = k0;
  sk[t + 256] = k1;
  __syncthreads();
  int r0 = 0, r1 = 0;
  for (int j = 0; j < 512; ++j) {  // LDS broadcast reads (lockstep j)
    u64 kj = sk[j];
    r0 += (kj < k0);
    r1 += (kj < k1);
  }
  const float* srow = d2 + (size_t)(BDIM + b) * NTOT;
  if (r0 < TOPK) {
    tvs[r0] = sqrtf(__uint_as_float((unsigned)(k0 >> 13)));
    svs[r0] = sqrtf(srow[(unsigned)(k0 & 8191u)]);
  }
  if (r1 < TOPK) {
    tvs[r1] = sqrtf(__uint_as_float((unsigned)(k1 >> 13)));
    svs[r1] = sqrtf(srow[(unsigned)(k1 & 8191u)]);
  }
  __syncthreads();
  float val = 0.f;
  if (t >= 1 && t < TOPK) {
    float tv = tvs[t], sv = svs[t];
    float tr = 0.f, sr = 0.f;
    for (int j = 0; j < TOPK; ++j) {
      tr += fmaxf(tv - tvs[j], 0.f);
      sr += fmaxf(sv - svs[j], 0.f);
    }
    tr -= fmaxf(tv - tvs[0], 0.f);  // exclude min pair (reference uses [1:])
    sr -= fmaxf(sv - svs[0], 0.f);
    float d = tr - sr;
    val = d * d;
  }
  int lane = t & 63, w = t >> 6;
  for (int off = 1; off < 64; off <<= 1) val += __shfl_xor(val, off);
  if (lane == 0) red[w] = val;  // threads >=128 contribute 0
  __syncthreads();
  if (t == 0) {
    float sum = red[0] + red[1];
    float contrib = (1.f / 256.f) * fabsf(svs[0] - tvs[0]) +
                    (1.f / (127.f * 256.f)) * sqrtf(sum);
    atomicAdd(out, contrib);
  }
}

// ---------------- launch ----------------------------------------------------
extern "C" void kernel_launch(void* const* d_in, const int* in_sizes, int n_in,
                              void* d_out, int out_size, void* d_ws,
                              size_t ws_size, hipStream_t stream) {
  const float* f_s = (const float*)d_in[0];
  const float* f_t = (const float*)d_in[1];
  const float* gallery = (const float*)d_in[2];
  float* out = (float*)d_out;

  float* d2 = (float*)d_ws;                            // 512*8192 f32 (16 MB)
  short* Abf = (short*)(d2 + (size_t)512 * NTOT);      // 512*2048 bf16 (2 MB)
  short* Bbf = Abf + (size_t)512 * DDIM;               // 8192*2048 bf16 (32 MB)
  float* normA = (float*)(Bbf + (size_t)NTOT * DDIM);  // 512
  float* galnorm = normA + 512;                        // 8192
  u64* cand = (u64*)(galnorm + NTOT);                  // 256*512 u64 (1 MB)

  hipMemsetAsync(d_out, 0, sizeof(float), stream);

  k_prep_gal<<<NGAL / 4 + BDIM, 256, 0, stream>>>(f_t, f_s, gallery, Abf, Bbf,
                                                  normA, galnorm);
  k_gemm<<<dim3(NTOT / 128, 512 / 64), 256, 0, stream>>>(Abf, Bbf, normA,
                                                         galnorm, d2);
  k_part<<<dim3(4, BDIM), 256, 0, stream>>>(d2, cand);
  k_mloss<<<BDIM, 256, 0, stream>>>(cand, d2, out);
}

// Round 7
// 159.694 us; speedup vs baseline: 1.2936x; 1.0222x over previous
//
#include <hip/hip_runtime.h>
#include <hip/hip_bf16.h>

// B=256, d=2048, N0=7936, N=8192, K=128, P=2, ALPHA=BETA=1, EPS=1e-12
#define BDIM 256
#define DDIM 2048
#define NGAL 7936
#define NTOT 8192
#define TOPK 128
#define EPSC 1e-12f

typedef __attribute__((ext_vector_type(8))) short bf16x8;
typedef __attribute__((ext_vector_type(4))) float f32x4;
typedef unsigned long long u64;

// round-to-nearest-even fp32 -> bf16 (bit pattern in a short)
__device__ __forceinline__ short bfr(float x) {
  unsigned u = __float_as_uint(x);
  unsigned r = (u + 0x7FFFu + ((u >> 16) & 1u)) >> 16;
  return (short)r;
}

// ---------------- Kernel 1: gallery bf16+norms  +  teacher/student prep ----
__global__ __launch_bounds__(256) void k_prep_gal(
    const float* __restrict__ f_t, const float* __restrict__ f_s,
    const float* __restrict__ gallery, short* __restrict__ Abf,
    short* __restrict__ Bbf, float* __restrict__ normA,
    float* __restrict__ galnorm) {
  int bx = blockIdx.x, t = threadIdx.x;
  int lane = t & 63, wv = t >> 6;
  if (bx < NGAL / 4) {
    int row = bx * 4 + wv;
    const float4* g4 = (const float4*)(gallery + (size_t)row * DDIM);
    float s = 0.f;
    for (int i = lane; i < DDIM / 4; i += 64) {
      float4 v = g4[i];
      *(short4*)&Bbf[(size_t)row * DDIM + i * 4] =
          make_short4(bfr(v.x), bfr(v.y), bfr(v.z), bfr(v.w));
      s += v.x * v.x + v.y * v.y + v.z * v.z + v.w * v.w;
    }
    for (int off = 32; off; off >>= 1) s += __shfl_xor(s, off);
    if (lane == 0) galnorm[row] = s;
    return;
  }
  int b = bx - NGAL / 4;
  const float4* t4 = (const float4*)(f_t + (size_t)b * DDIM);
  const float4* s4 = (const float4*)(f_s + (size_t)b * DDIM);
  float st = 0.f, ss = 0.f;
  for (int i = t; i < DDIM / 4; i += 256) {
    float4 v = t4[i];
    float4 q = make_float4(v.x * v.x, v.y * v.y, v.z * v.z, v.w * v.w);
    short4 qb = make_short4(bfr(q.x), bfr(q.y), bfr(q.z), bfr(q.w));
    *(short4*)&Abf[(size_t)b * DDIM + i * 4] = qb;
    *(short4*)&Bbf[(size_t)(NGAL + b) * DDIM + i * 4] = qb;
    st += q.x * q.x + q.y * q.y + q.z * q.z + q.w * q.w;
    float4 u_ = s4[i];
    float4 r = make_float4(u_.x * u_.x, u_.y * u_.y, u_.z * u_.z, u_.w * u_.w);
    *(short4*)&Abf[(size_t)(BDIM + b) * DDIM + i * 4] =
        make_short4(bfr(r.x), bfr(r.y), bfr(r.z), bfr(r.w));
    ss += r.x * r.x + r.y * r.y + r.z * r.z + r.w * r.w;
  }
  for (int off = 32; off; off >>= 1) {
    st += __shfl_xor(st, off);
    ss += __shfl_xor(ss, off);
  }
  __shared__ float red[8];
  if (lane == 0) { red[wv] = st; red[4 + wv] = ss; }
  __syncthreads();
  if (t == 0) {
    float a = red[0] + red[1] + red[2] + red[3];
    float c = red[4] + red[5] + red[6] + red[7];
    normA[b] = a;
    galnorm[NGAL + b] = a;
    normA[BDIM + b] = c;
  }
}

// ---------------- Kernel 2: bf16 MFMA GEMM -> clipped squared distances ----
// 64(M)x128(N) tile, BK=64, 4 waves (2x2), double-buffered LDS via
// global_load_lds. 1-D grid with XCD-grouped decode: xcd = swz&7 owns n-tiles
// [8*xcd, 8*xcd+8); the 8 m-siblings of an n-tile dispatch consecutively on
// the same XCD -> B panel (512 KB) fetched once into that L2, 7 hits.
__global__ __launch_bounds__(256) void k_gemm(
    const short* __restrict__ Abf, const short* __restrict__ Bbf,
    const float* __restrict__ normA, const float* __restrict__ galnorm,
    float* __restrict__ d2) {
  __shared__ short S[2][12288];  // [0,4096): A 64x64 ; [4096,12288): B 128x64
  int t = threadIdx.x;
  int swz = blockIdx.x;
  int xcd = swz & 7, p = swz >> 3;
  int nt = xcd * 8 + (p >> 3);  // [0,64)
  int mt = p & 7;               // [0,8)
  int n0 = nt * 128, m0 = mt * 64;
  int lane = t & 63, wid = t >> 6;
  int wm = wid >> 1, wn = wid & 1;

  const short* gb[6];
  int lof[6];
#pragma unroll
  for (int q = 0; q < 6; ++q) {
    int c = t + q * 256;
    int r, j;
    const short* base;
    if (c < 512) {
      r = c >> 3; j = c & 7;
      base = Abf + (size_t)(m0 + r) * DDIM;
    } else {
      int cb = c - 512;
      r = cb >> 3; j = cb & 7;
      base = Bbf + (size_t)(n0 + r) * DDIM;
    }
    gb[q] = base + ((j * 8) ^ ((r & 7) << 3));
    lof[q] = c * 8;
  }

  int fr = lane & 15, fk = (lane >> 4) * 8;
  int axor = (fr & 7) << 3;
  f32x4 acc[2][4] = {};

#define STAGE(buf, kt)                                                       \
  {                                                                          \
    _Pragma("unroll") for (int q = 0; q < 6; ++q)                            \
        __builtin_amdgcn_global_load_lds(                                    \
            (const __attribute__((address_space(1))) void*)(gb[q] + (kt)),   \
            (__attribute__((address_space(3))) void*)(&S[buf][lof[q]]), 16,  \
            0, 0);                                                           \
  }

  STAGE(0, 0);
  __syncthreads();
  int cur = 0;
  for (int it = 0; it < DDIM / 64; ++it) {
    if (it + 1 < DDIM / 64) STAGE(cur ^ 1, (it + 1) * 64);
#pragma unroll
    for (int ks = 0; ks < 2; ++ks) {
      int ko = (ks * 32 + fk) ^ axor;
      bf16x8 av[2], bv[4];
#pragma unroll
      for (int mi = 0; mi < 2; ++mi)
        av[mi] = *(const bf16x8*)&S[cur][(wm * 32 + mi * 16 + fr) * 64 + ko];
#pragma unroll
      for (int ni = 0; ni < 4; ++ni)
        bv[ni] =
            *(const bf16x8*)&S[cur][4096 + (wn * 64 + ni * 16 + fr) * 64 + ko];
#pragma unroll
      for (int mi = 0; mi < 2; ++mi)
#pragma unroll
        for (int ni = 0; ni < 4; ++ni)
          acc[mi][ni] = __builtin_amdgcn_mfma_f32_16x16x32_bf16(
              av[mi], bv[ni], acc[mi][ni], 0, 0, 0);
    }
    __syncthreads();
    cur ^= 1;
  }
  int rrow = (lane >> 4) * 4;
#pragma unroll
  for (int mi = 0; mi < 2; ++mi) {
#pragma unroll
    for (int r = 0; r < 4; ++r) {
      int m = m0 + wm * 32 + mi * 16 + rrow + r;
      float nm = normA[m];
#pragma unroll
      for (int ni = 0; ni < 4; ++ni) {
        int n = n0 + wn * 64 + ni * 16 + fr;
        float v = nm + galnorm[n] - 2.0f * acc[mi][ni][r];
        v = fmaxf(v, EPSC);
        if (m < BDIM && n == NGAL + m) v = EPSC;  // exact self-match pin
        d2[(size_t)m * NTOT + n] = v;
      }
    }
  }
#undef STAGE
}

// ---------------- Kernel 3: per-chunk exact top-128, 3-pass value radix ----
// Block (c, b): columns [c*2048,(c+1)*2048) of teacher row b. Radix-select on
// the 32-bit VALUE only (11+11+10 bits = 3 passes); exact index tie-break via
// equals post-pass (take kneed smallest indices among u == v*). Output slots
// unordered (k_mloss is order-free). Permuted hist slots keep the summation
// phase conflict-free; plain atomics (leader-aggregation regressed, r5).
__global__ __launch_bounds__(256) void k_part(
    const float* __restrict__ d2, u64* __restrict__ cand) {
  __shared__ unsigned rowu[2048];
  __shared__ unsigned hist[2][2048];
  __shared__ unsigned wsum[4];
  __shared__ unsigned s_pref, s_kneed, s_cnt, s_eqcnt;
  __shared__ unsigned short eqidx[256];
  int c = blockIdx.x, b = blockIdx.y, t = threadIdx.x;
  int lane = t & 63, w = t >> 6;
  const uint4* src = (const uint4*)(d2 + (size_t)b * NTOT + c * 2048);
  ((uint4*)rowu)[t] = src[t];
  ((uint4*)rowu)[t + 256] = src[t + 256];
  if (t == 0) { s_pref = 0; s_kneed = TOPK; s_cnt = 0; s_eqcnt = 0; }
#pragma unroll 1
  for (int p = 0; p < 3; ++p) {
    int sh = (p == 0) ? 21 : (p == 1) ? 10 : 0;
    uint4 z4 = make_uint4(0, 0, 0, 0);
    ((uint4*)&hist[0][0])[t] = z4;
    ((uint4*)&hist[0][0])[t + 256] = z4;
    ((uint4*)&hist[0][0])[t + 512] = z4;
    ((uint4*)&hist[0][0])[t + 768] = z4;
    __syncthreads();  // zero + rowu + prev winner visible
    unsigned pref = s_pref, kn = s_kneed;
    int sh_hi = (p == 1) ? 21 : 10;  // unused for p==0
    unsigned bmask = (p == 2) ? 1023u : 2047u;
#pragma unroll
    for (int s = 0; s < 8; ++s) {
      unsigned u = rowu[t + s * 256];
      bool sel = (p == 0) || ((u >> sh_hi) == pref);
      if (sel) {
        unsigned bin = (u >> sh) & bmask;
        unsigned slot = ((bin & 7u) << 8) | (bin >> 3);  // conflict-free sums
        atomicAdd(&hist[w & 1][slot], 1u);
      }
    }
    __syncthreads();
    unsigned ls = 0;  // sum of bins [8t, 8t+8) == slots q*256+t
#pragma unroll
    for (int q = 0; q < 8; ++q)
      ls += hist[0][q * 256 + t] + hist[1][q * 256 + t];
    unsigned incl = ls;
    for (int off = 1; off < 64; off <<= 1) {
      unsigned x = __shfl_up(incl, off);
      if (lane >= off) incl += x;
    }
    if (lane == 63) wsum[w] = incl;
    __syncthreads();
    unsigned woff = 0;
    for (int ww = 0; ww < w; ++ww) woff += wsum[ww];
    incl += woff;
    unsigned excl = incl - ls;
    if (excl < kn && kn <= incl) {  // unique winner thread
      unsigned re = excl, binj = 0;
      for (int q = 0; q < 8; ++q) {
        unsigned h = hist[0][q * 256 + t] + hist[1][q * 256 + t];
        if (kn <= re + h) { binj = ((unsigned)t << 3) | (unsigned)q; break; }
        re += h;
      }
      unsigned bits = (p == 2) ? 10u : 11u;
      s_pref = (pref << bits) | binj;
      s_kneed = kn - re;
    }
    __syncthreads();
  }
  unsigned vstar = s_pref;   // exact value of the local 128th-smallest
  unsigned kneed = s_kneed;  // # equals to take (smallest indices first)
  u64* dst = cand + ((size_t)b * 4 + c) * TOPK;
#pragma unroll 1
  for (int s = 0; s < 8; ++s) {
    int i = t + s * 256;
    unsigned u = rowu[i];
    bool lt = (u < vstar);
    u64 mlt = __ballot(lt);
    unsigned basep;
    if (lane == 0) basep = atomicAdd(&s_cnt, (unsigned)__popcll(mlt));
    basep = (unsigned)__shfl((int)basep, 0);
    if (lt) {
      unsigned pos = basep + (unsigned)__popcll(mlt & ((1ull << lane) - 1));
      dst[pos] = ((u64)u << 13) | (unsigned)(c * 2048 + i);
    }
    if (u == vstar) {
      unsigned e = atomicAdd(&s_eqcnt, 1u);
      if (e < 256) eqidx[e] = (unsigned short)i;
    }
  }
  __syncthreads();
  unsigned ce = s_eqcnt;
  if (ce > 256) ce = 256;
  if (t < (int)ce) {
    unsigned short my = eqidx[t];
    unsigned rank = 0;
    for (unsigned j = 0; j < ce; ++j) rank += (eqidx[j] < my);
    if (rank < kneed) {
      unsigned pos = atomicAdd(&s_cnt, 1u);
      dst[pos] = ((u64)vstar << 13) | (unsigned)(c * 2048 + (int)my);
    }
  }
}

// ---------------- Kernel 4: sort-free merge + loss -------------------------
// 512 unique candidate keys per row; global rank of key = #{smaller keys}
// (exact for ranks < 128 since every globally-smaller key is present).
// rank r < 128 -> slot r. Loss is order-free given the min pair (rank 0).
__global__ __launch_bounds__(256) void k_mloss(
    const u64* __restrict__ cand, const float* __restrict__ d2,
    float* __restrict__ out) {
  __shared__ u64 sk[512];
  __shared__ float tvs[TOPK], svs[TOPK], red[2];
  int b = blockIdx.x, t = threadIdx.x;
  u64 k0 = cand[(size_t)b * 512 + t];
  u64 k1 = cand[(size_t)b * 512 + 256 + t];
  sk[t] = k0;
  sk[t + 256] = k1;
  __syncthreads();
  int r0 = 0, r1 = 0;
  for (int j = 0; j < 512; ++j) {  // LDS broadcast reads (lockstep j)
    u64 kj = sk[j];
    r0 += (kj < k0);
    r1 += (kj < k1);
  }
  const float* srow = d2 + (size_t)(BDIM + b) * NTOT;
  if (r0 < TOPK) {
    tvs[r0] = sqrtf(__uint_as_float((unsigned)(k0 >> 13)));
    svs[r0] = sqrtf(srow[(unsigned)(k0 & 8191u)]);
  }
  if (r1 < TOPK) {
    tvs[r1] = sqrtf(__uint_as_float((unsigned)(k1 >> 13)));
    svs[r1] = sqrtf(srow[(unsigned)(k1 & 8191u)]);
  }
  __syncthreads();
  float val = 0.f;
  if (t >= 1 && t < TOPK) {
    float tv = tvs[t], sv = svs[t];
    float tr = 0.f, sr = 0.f;
    for (int j = 0; j < TOPK; ++j) {
      tr += fmaxf(tv - tvs[j], 0.f);
      sr += fmaxf(sv - svs[j], 0.f);
    }
    tr -= fmaxf(tv - tvs[0], 0.f);  // exclude min pair (reference uses [1:])
    sr -= fmaxf(sv - svs[0], 0.f);
    float d = tr - sr;
    val = d * d;
  }
  int lane = t & 63, w = t >> 6;
  for (int off = 1; off < 64; off <<= 1) val += __shfl_xor(val, off);
  if (lane == 0) red[w] = val;  // threads >=128 contribute 0
  __syncthreads();
  if (t == 0) {
    float sum = red[0] + red[1];
    float contrib = (1.f / 256.f) * fabsf(svs[0] - tvs[0]) +
                    (1.f / (127.f * 256.f)) * sqrtf(sum);
    atomicAdd(out, contrib);
  }
}

// ---------------- launch ----------------------------------------------------
extern "C" void kernel_launch(void* const* d_in, const int* in_sizes, int n_in,
                              void* d_out, int out_size, void* d_ws,
                              size_t ws_size, hipStream_t stream) {
  const float* f_s = (const float*)d_in[0];
  const float* f_t = (const float*)d_in[1];
  const float* gallery = (const float*)d_in[2];
  float* out = (float*)d_out;

  float* d2 = (float*)d_ws;                            // 512*8192 f32 (16 MB)
  short* Abf = (short*)(d2 + (size_t)512 * NTOT);      // 512*2048 bf16 (2 MB)
  short* Bbf = Abf + (size_t)512 * DDIM;               // 8192*2048 bf16 (32 MB)
  float* normA = (float*)(Bbf + (size_t)NTOT * DDIM);  // 512
  float* galnorm = normA + 512;                        // 8192
  u64* cand = (u64*)(galnorm + NTOT);                  // 256*512 u64 (1 MB)

  hipMemsetAsync(d_out, 0, sizeof(float), stream);

  k_prep_gal<<<NGAL / 4 + BDIM, 256, 0, stream>>>(f_t, f_s, gallery, Abf, Bbf,
                                                  normA, galnorm);
  k_gemm<<<512, 256, 0, stream>>>(Abf, Bbf, normA, galnorm, d2);
  k_part<<<dim3(4, BDIM), 256, 0, stream>>>(d2, cand);
  k_mloss<<<BDIM, 256, 0, stream>>>(cand, d2, out);
}

// Round 8
// 157.687 us; speedup vs baseline: 1.3101x; 1.0127x over previous
//
#include <hip/hip_runtime.h>
#include <hip/hip_bf16.h>

// B=256, d=2048, N0=7936, N=8192, K=128, P=2, ALPHA=BETA=1, EPS=1e-12
#define BDIM 256
#define DDIM 2048
#define NGAL 7936
#define NTOT 8192
#define TOPK 128
#define EPSC 1e-12f

typedef __attribute__((ext_vector_type(8))) short bf16x8;
typedef __attribute__((ext_vector_type(4))) float f32x4;
typedef unsigned long long u64;

// round-to-nearest-even fp32 -> bf16 (bit pattern in a short)
__device__ __forceinline__ short bfr(float x) {
  unsigned u = __float_as_uint(x);
  unsigned r = (u + 0x7FFFu + ((u >> 16) & 1u)) >> 16;
  return (short)r;
}

// ---------------- Kernel 1: gallery bf16+norms  +  teacher/student prep ----
__global__ __launch_bounds__(256) void k_prep_gal(
    const float* __restrict__ f_t, const float* __restrict__ f_s,
    const float* __restrict__ gallery, short* __restrict__ Abf,
    short* __restrict__ Bbf, float* __restrict__ normA,
    float* __restrict__ galnorm) {
  int bx = blockIdx.x, t = threadIdx.x;
  int lane = t & 63, wv = t >> 6;
  if (bx < NGAL / 4) {
    int row = bx * 4 + wv;
    const float4* g4 = (const float4*)(gallery + (size_t)row * DDIM);
    float s = 0.f;
    for (int i = lane; i < DDIM / 4; i += 64) {
      float4 v = g4[i];
      *(short4*)&Bbf[(size_t)row * DDIM + i * 4] =
          make_short4(bfr(v.x), bfr(v.y), bfr(v.z), bfr(v.w));
      s += v.x * v.x + v.y * v.y + v.z * v.z + v.w * v.w;
    }
    for (int off = 32; off; off >>= 1) s += __shfl_xor(s, off);
    if (lane == 0) galnorm[row] = s;
    return;
  }
  int b = bx - NGAL / 4;
  const float4* t4 = (const float4*)(f_t + (size_t)b * DDIM);
  const float4* s4 = (const float4*)(f_s + (size_t)b * DDIM);
  float st = 0.f, ss = 0.f;
  for (int i = t; i < DDIM / 4; i += 256) {
    float4 v = t4[i];
    float4 q = make_float4(v.x * v.x, v.y * v.y, v.z * v.z, v.w * v.w);
    short4 qb = make_short4(bfr(q.x), bfr(q.y), bfr(q.z), bfr(q.w));
    *(short4*)&Abf[(size_t)b * DDIM + i * 4] = qb;
    *(short4*)&Bbf[(size_t)(NGAL + b) * DDIM + i * 4] = qb;
    st += q.x * q.x + q.y * q.y + q.z * q.z + q.w * q.w;
    float4 u_ = s4[i];
    float4 r = make_float4(u_.x * u_.x, u_.y * u_.y, u_.z * u_.z, u_.w * u_.w);
    *(short4*)&Abf[(size_t)(BDIM + b) * DDIM + i * 4] =
        make_short4(bfr(r.x), bfr(r.y), bfr(r.z), bfr(r.w));
    ss += r.x * r.x + r.y * r.y + r.z * r.z + r.w * r.w;
  }
  for (int off = 32; off; off >>= 1) {
    st += __shfl_xor(st, off);
    ss += __shfl_xor(ss, off);
  }
  __shared__ float red[8];
  if (lane == 0) { red[wv] = st; red[4 + wv] = ss; }
  __syncthreads();
  if (t == 0) {
    float a = red[0] + red[1] + red[2] + red[3];
    float c = red[4] + red[5] + red[6] + red[7];
    normA[b] = a;
    galnorm[NGAL + b] = a;
    normA[BDIM + b] = c;
  }
}

// ---------------- Kernel 2: bf16 MFMA GEMM -> clipped squared distances ----
// 128x128 tile, BK=64, 8 waves (2m x 4n, wave-tile 64x32), double-buffered
// LDS via global_load_lds (linear dest, pre-swizzled source, swizzled reads).
// Halves staged L2 bytes per FLOP vs 64x128 (tile perimeter/area). XCD-grouped
// decode: xcd owns 8 n-panels; 4 m-siblings dispatch consecutively.
__global__ __launch_bounds__(512) void k_gemm(
    const short* __restrict__ Abf, const short* __restrict__ Bbf,
    const float* __restrict__ normA, const float* __restrict__ galnorm,
    float* __restrict__ d2) {
  __shared__ short S[2][16384];  // A 128x64 at [0,8192); B 128x64 at +8192
  int t = threadIdx.x;
  int swz = blockIdx.x;
  int xcd = swz & 7, p = swz >> 3;
  int nt = xcd * 8 + (p >> 2);  // [0,64)
  int mt = p & 3;               // [0,4)
  int n0 = nt * 128, m0 = mt * 128;
  int lane = t & 63, wid = t >> 6;
  int wm = wid >> 2, wn = wid & 3;

  const short* gb[4];
  int lof[4];
#pragma unroll
  for (int q = 0; q < 4; ++q) {
    int c = t + q * 512;
    int r, j;
    const short* base;
    if (c < 1024) {  // A: 128 rows x 8 chunks
      r = c >> 3; j = c & 7;
      base = Abf + (size_t)(m0 + r) * DDIM;
      lof[q] = c * 8;
    } else {         // B: 128 rows x 8 chunks
      int cb = c - 1024;
      r = cb >> 3; j = cb & 7;
      base = Bbf + (size_t)(n0 + r) * DDIM;
      lof[q] = 8192 + cb * 8;
    }
    gb[q] = base + ((j * 8) ^ ((r & 7) << 3));  // pre-swizzled global column
  }

  int fr = lane & 15, fk = (lane >> 4) * 8;
  int axor = (fr & 7) << 3;
  f32x4 acc[4][2] = {};

#define STAGE(buf, kt)                                                       \
  {                                                                          \
    _Pragma("unroll") for (int q = 0; q < 4; ++q)                            \
        __builtin_amdgcn_global_load_lds(                                    \
            (const __attribute__((address_space(1))) void*)(gb[q] + (kt)),   \
            (__attribute__((address_space(3))) void*)(&S[buf][lof[q]]), 16,  \
            0, 0);                                                           \
  }

  STAGE(0, 0);
  __syncthreads();
  int cur = 0;
  for (int it = 0; it < DDIM / 64; ++it) {
    if (it + 1 < DDIM / 64) STAGE(cur ^ 1, (it + 1) * 64);
#pragma unroll
    for (int ks = 0; ks < 2; ++ks) {
      int ko = (ks * 32 + fk) ^ axor;
      bf16x8 av[4], bv[2];
#pragma unroll
      for (int mi = 0; mi < 4; ++mi)
        av[mi] = *(const bf16x8*)&S[cur][(wm * 64 + mi * 16 + fr) * 64 + ko];
#pragma unroll
      for (int ni = 0; ni < 2; ++ni)
        bv[ni] =
            *(const bf16x8*)&S[cur][8192 + (wn * 32 + ni * 16 + fr) * 64 + ko];
#pragma unroll
      for (int mi = 0; mi < 4; ++mi)
#pragma unroll
        for (int ni = 0; ni < 2; ++ni)
          acc[mi][ni] = __builtin_amdgcn_mfma_f32_16x16x32_bf16(
              av[mi], bv[ni], acc[mi][ni], 0, 0, 0);
    }
    __syncthreads();  // drains gload_lds (vmcnt) + lds reads; swap safe
    cur ^= 1;
  }
  // epilogue: C/D map col=lane&15 (n), row=(lane>>4)*4+reg (m)
  int rrow = (lane >> 4) * 4;
#pragma unroll
  for (int mi = 0; mi < 4; ++mi) {
#pragma unroll
    for (int r = 0; r < 4; ++r) {
      int m = m0 + wm * 64 + mi * 16 + rrow + r;
      float nm = normA[m];
#pragma unroll
      for (int ni = 0; ni < 2; ++ni) {
        int n = n0 + wn * 32 + ni * 16 + fr;
        float v = nm + galnorm[n] - 2.0f * acc[mi][ni][r];
        v = fmaxf(v, EPSC);
        if (m < BDIM && n == NGAL + m) v = EPSC;  // exact self-match pin
        d2[(size_t)m * NTOT + n] = v;
      }
    }
  }
#undef STAGE
}

// ---------------- Kernel 3: per-chunk exact top-128, 3-pass value radix ----
// Also zeroes d_out (stream-ordered before k_mloss) -- saves a memset launch.
__global__ __launch_bounds__(256) void k_part(
    const float* __restrict__ d2, u64* __restrict__ cand,
    float* __restrict__ out) {
  __shared__ unsigned rowu[2048];
  __shared__ unsigned hist[2][2048];
  __shared__ unsigned wsum[4];
  __shared__ unsigned s_pref, s_kneed, s_cnt, s_eqcnt;
  __shared__ unsigned short eqidx[256];
  int c = blockIdx.x, b = blockIdx.y, t = threadIdx.x;
  if (c == 0 && b == 0 && t == 0) *out = 0.f;
  int lane = t & 63, w = t >> 6;
  const uint4* src = (const uint4*)(d2 + (size_t)b * NTOT + c * 2048);
  ((uint4*)rowu)[t] = src[t];
  ((uint4*)rowu)[t + 256] = src[t + 256];
  if (t == 0) { s_pref = 0; s_kneed = TOPK; s_cnt = 0; s_eqcnt = 0; }
#pragma unroll 1
  for (int p = 0; p < 3; ++p) {
    int sh = (p == 0) ? 21 : (p == 1) ? 10 : 0;
    uint4 z4 = make_uint4(0, 0, 0, 0);
    ((uint4*)&hist[0][0])[t] = z4;
    ((uint4*)&hist[0][0])[t + 256] = z4;
    ((uint4*)&hist[0][0])[t + 512] = z4;
    ((uint4*)&hist[0][0])[t + 768] = z4;
    __syncthreads();  // zero + rowu + prev winner visible
    unsigned pref = s_pref, kn = s_kneed;
    int sh_hi = (p == 1) ? 21 : 10;  // unused for p==0
    unsigned bmask = (p == 2) ? 1023u : 2047u;
#pragma unroll
    for (int s = 0; s < 8; ++s) {
      unsigned u = rowu[t + s * 256];
      bool sel = (p == 0) || ((u >> sh_hi) == pref);
      if (sel) {
        unsigned bin = (u >> sh) & bmask;
        unsigned slot = ((bin & 7u) << 8) | (bin >> 3);  // conflict-free sums
        atomicAdd(&hist[w & 1][slot], 1u);
      }
    }
    __syncthreads();
    unsigned ls = 0;  // sum of bins [8t, 8t+8) == slots q*256+t
#pragma unroll
    for (int q = 0; q < 8; ++q)
      ls += hist[0][q * 256 + t] + hist[1][q * 256 + t];
    unsigned incl = ls;
    for (int off = 1; off < 64; off <<= 1) {
      unsigned x = __shfl_up(incl, off);
      if (lane >= off) incl += x;
    }
    if (lane == 63) wsum[w] = incl;
    __syncthreads();
    unsigned woff = 0;
    for (int ww = 0; ww < w; ++ww) woff += wsum[ww];
    incl += woff;
    unsigned excl = incl - ls;
    if (excl < kn && kn <= incl) {  // unique winner thread
      unsigned re = excl, binj = 0;
      for (int q = 0; q < 8; ++q) {
        unsigned h = hist[0][q * 256 + t] + hist[1][q * 256 + t];
        if (kn <= re + h) { binj = ((unsigned)t << 3) | (unsigned)q; break; }
        re += h;
      }
      unsigned bits = (p == 2) ? 10u : 11u;
      s_pref = (pref << bits) | binj;
      s_kneed = kn - re;
    }
    __syncthreads();
  }
  unsigned vstar = s_pref;   // exact value of the local 128th-smallest
  unsigned kneed = s_kneed;  // # equals to take (smallest indices first)
  u64* dst = cand + ((size_t)b * 4 + c) * TOPK;
#pragma unroll 1
  for (int s = 0; s < 8; ++s) {
    int i = t + s * 256;
    unsigned u = rowu[i];
    bool lt = (u < vstar);
    u64 mlt = __ballot(lt);
    unsigned basep;
    if (lane == 0) basep = atomicAdd(&s_cnt, (unsigned)__popcll(mlt));
    basep = (unsigned)__shfl((int)basep, 0);
    if (lt) {
      unsigned pos = basep + (unsigned)__popcll(mlt & ((1ull << lane) - 1));
      dst[pos] = ((u64)u << 13) | (unsigned)(c * 2048 + i);
    }
    if (u == vstar) {
      unsigned e = atomicAdd(&s_eqcnt, 1u);
      if (e < 256) eqidx[e] = (unsigned short)i;
    }
  }
  __syncthreads();
  unsigned ce = s_eqcnt;
  if (ce > 256) ce = 256;
  if (t < (int)ce) {
    unsigned short my = eqidx[t];
    unsigned rank = 0;
    for (unsigned j = 0; j < ce; ++j) rank += (eqidx[j] < my);
    if (rank < kneed) {
      unsigned pos = atomicAdd(&s_cnt, 1u);
      dst[pos] = ((u64)vstar << 13) | (unsigned)(c * 2048 + (int)my);
    }
  }
}

// ---------------- Kernel 4: sort-free merge + loss -------------------------
__global__ __launch_bounds__(256) void k_mloss(
    const u64* __restrict__ cand, const float* __restrict__ d2,
    float* __restrict__ out) {
  __shared__ u64 sk[512];
  __shared__ float tvs[TOPK], svs[TOPK], red[2];
  int b = blockIdx.x, t = threadIdx.x;
  u64 k0 = cand[(size_t)b * 512 + t];
  u64 k1 = cand[(size_t)b * 512 + 256 + t];
  sk[t] = k0;
  sk[t + 256] = k1;
  __syncthreads();
  int r0 = 0, r1 = 0;
  for (int j = 0; j < 512; ++j) {  // LDS broadcast reads (lockstep j)
    u64 kj = sk[j];
    r0 += (kj < k0);
    r1 += (kj < k1);
  }
  const float* srow = d2 + (size_t)(BDIM + b) * NTOT;
  if (r0 < TOPK) {
    tvs[r0] = sqrtf(__uint_as_float((unsigned)(k0 >> 13)));
    svs[r0] = sqrtf(srow[(unsigned)(k0 & 8191u)]);
  }
  if (r1 < TOPK) {
    tvs[r1] = sqrtf(__uint_as_float((unsigned)(k1 >> 13)));
    svs[r1] = sqrtf(srow[(unsigned)(k1 & 8191u)]);
  }
  __syncthreads();
  float val = 0.f;
  if (t >= 1 && t < TOPK) {
    float tv = tvs[t], sv = svs[t];
    float tr = 0.f, sr = 0.f;
    for (int j = 0; j < TOPK; ++j) {
      tr += fmaxf(tv - tvs[j], 0.f);
      sr += fmaxf(sv - svs[j], 0.f);
    }
    tr -= fmaxf(tv - tvs[0], 0.f);  // exclude min pair (reference uses [1:])
    sr -= fmaxf(sv - svs[0], 0.f);
    float d = tr - sr;
    val = d * d;
  }
  int lane = t & 63, w = t >> 6;
  for (int off = 1; off < 64; off <<= 1) val += __shfl_xor(val, off);
  if (lane == 0) red[w] = val;  // threads >=128 contribute 0
  __syncthreads();
  if (t == 0) {
    float sum = red[0] + red[1];
    float contrib = (1.f / 256.f) * fabsf(svs[0] - tvs[0]) +
                    (1.f / (127.f * 256.f)) * sqrtf(sum);
    atomicAdd(out, contrib);
  }
}

// ---------------- launch ----------------------------------------------------
extern "C" void kernel_launch(void* const* d_in, const int* in_sizes, int n_in,
                              void* d_out, int out_size, void* d_ws,
                              size_t ws_size, hipStream_t stream) {
  const float* f_s = (const float*)d_in[0];
  const float* f_t = (const float*)d_in[1];
  const float* gallery = (const float*)d_in[2];
  float* out = (float*)d_out;

  float* d2 = (float*)d_ws;                            // 512*8192 f32 (16 MB)
  short* Abf = (short*)(d2 + (size_t)512 * NTOT);      // 512*2048 bf16 (2 MB)
  short* Bbf = Abf + (size_t)512 * DDIM;               // 8192*2048 bf16 (32 MB)
  float* normA = (float*)(Bbf + (size_t)NTOT * DDIM);  // 512
  float* galnorm = normA + 512;                        // 8192
  u64* cand = (u64*)(galnorm + NTOT);                  // 256*512 u64 (1 MB)

  k_prep_gal<<<NGAL / 4 + BDIM, 256, 0, stream>>>(f_t, f_s, gallery, Abf, Bbf,
                                                  normA, galnorm);
  k_gemm<<<256, 512, 0, stream>>>(Abf, Bbf, normA, galnorm, d2);
  k_part<<<dim3(4, BDIM), 256, 0, stream>>>(d2, cand, out);
  k_mloss<<<BDIM, 256, 0, stream>>>(cand, d2, out);
}